// Round 15
// baseline (232.043 us; speedup 1.0000x reference)
//
#include <hip/hip_runtime.h>

// KCenterSampler FPS — scalar-cache (K$->L2) probe poll + per-wave winner
// (no barrier-2), with bounded scalar attempt + R4-proven LLC fallback.
//
// Mechanism: publisher PLAIN-stores the winner key -> dirty line in the
// shared XCD L2. Pollers read it via the SCALAR path: s_dcache_inv +
// s_load_dwordx2 x16 (whole 128B row -> SGPRs) — s_load goes K$->L2, so a
// same-XCD reader sees the dirty line at ~L2 latency. (R13 lesson: sc0
// VECTOR loads are agent-coherent -> serviced at LLC; plain vector loads
// stick in the non-coherent per-CU L1. The scalar path is the only cheap
// L2-visible read.) Every step ALSO publishes to the agent-scope LLC slot
// (R4-proven visible): the vector LLC poll is the unconditional fallback,
// the scalar attempt is bounded (8 iters), and a 2-strike latch disables
// it if co-location (b = bid&7 -> one XCD) turns out false. No deadlock,
// bounded regression.
//
// Per-wave winner: all 4 waves poll + scan independently (write-once slots,
// deterministic max) -> no far_s broadcast, no barrier 2. wk[] reuse is
// race-free: a wave can only pass poll(s) after its own block published(s),
// which happens after tid0 read wk(s).
//
// Everything else identical to R13/R14 (passed, absmax 0): fused gather,
// coords/sq/dist in VGPRs (waves_per_eu(1,1) + launder), DPP reductions,
// packed (monotone-dist, NPTS-j) u64 keys, first-index tie-break.

#define NPTS 6272
#define CDIM 35
#define BT   8
#define KSEL 128
#define THW  12544
#define BPS  16                  // blocks per segment
#define PPB  392                 // points per block
#define BLK  256
#define NB   (BT * BPS)          // 128 blocks
#define TAILN (PPB - BLK)        // 136: threads owning a 2nd point

__device__ __forceinline__ unsigned long long key_of(float v, int j) {
  unsigned int u = __float_as_uint(v);
  u = (u & 0x80000000u) ? ~u : (u | 0x80000000u);   // monotone float->uint
  return ((unsigned long long)u << 32) | (unsigned int)(NPTS - j); // both words !=0
}
__device__ __forceinline__ unsigned long long kmax(unsigned long long a,
                                                   unsigned long long b) {
  return a > b ? a : b;
}
__device__ __forceinline__ unsigned long long merge64(unsigned long long a,
                                                      unsigned long long t) {
  unsigned int lo = (unsigned int)a > (unsigned int)t ? (unsigned int)a : (unsigned int)t;
  unsigned int ah = (unsigned int)(a >> 32), th = (unsigned int)(t >> 32);
  unsigned int hi = ah > th ? ah : th;
  return ((unsigned long long)hi << 32) | lo;
}

template <int CTRL, int RMASK, bool BC>
__device__ __forceinline__ unsigned long long dpp_kmax(unsigned long long k) {
  unsigned int lo = (unsigned int)k, hi = (unsigned int)(k >> 32);
  unsigned int tlo = (unsigned int)__builtin_amdgcn_update_dpp(0, (int)lo, CTRL, RMASK, 0xF, BC);
  unsigned int thi = (unsigned int)__builtin_amdgcn_update_dpp(0, (int)hi, CTRL, RMASK, 0xF, BC);
  unsigned long long t = ((unsigned long long)thi << 32) | tlo;
  return kmax(k, t);
}
__device__ __forceinline__ unsigned long long wave_kmax64(unsigned long long k) {
  k = dpp_kmax<0x111, 0xF, true >(k);
  k = dpp_kmax<0x112, 0xF, true >(k);
  k = dpp_kmax<0x114, 0xF, true >(k);
  k = dpp_kmax<0x118, 0xF, true >(k);
  k = dpp_kmax<0x142, 0xA, false>(k);
  k = dpp_kmax<0x143, 0xC, false>(k);
  unsigned int rlo = (unsigned int)__builtin_amdgcn_readlane((int)(unsigned int)k, 63);
  unsigned int rhi = (unsigned int)__builtin_amdgcn_readlane((int)(k >> 32), 63);
  return ((unsigned long long)rhi << 32) | rlo;
}
__device__ __forceinline__ unsigned long long row16_kmax(unsigned long long k) {
  k = dpp_kmax<0x111, 0xF, true>(k);
  k = dpp_kmax<0x112, 0xF, true>(k);
  k = dpp_kmax<0x114, 0xF, true>(k);
  k = dpp_kmax<0x118, 0xF, true>(k);
  unsigned int rlo = (unsigned int)__builtin_amdgcn_readlane((int)(unsigned int)k, 15);
  unsigned int rhi = (unsigned int)__builtin_amdgcn_readlane((int)(k >> 32), 15);
  return ((unsigned long long)rhi << 32) | rlo;
}

__device__ __forceinline__ unsigned long long load_llc(const unsigned long long* p) {
  unsigned long long r;
  asm volatile("global_load_dwordx2 %0, %1, off sc0 sc1\n\ts_waitcnt vmcnt(0)"
               : "=&v"(r) : "v"(p) : "memory");
  return r;
}
__device__ __forceinline__ void store_plain(unsigned long long* p, unsigned long long v) {
  asm volatile("global_store_dwordx2 %0, %1, off" :: "v"(p), "v"(v) : "memory");
}

__global__ __attribute__((amdgpu_waves_per_eu(1, 1))) __launch_bounds__(BLK)
void fps_kernel(const float* __restrict__ x,
                const int* __restrict__ init_,
                float* __restrict__ patches,
                float* __restrict__ sidx,
                unsigned long long* __restrict__ slots,
                unsigned long long* __restrict__ probe) {
  __shared__ unsigned long long wk[4];

  const int bid  = (int)blockIdx.x;
  const int b    = bid & 7;            // segment: round-robin -> same XCD
  const int sub  = bid >> 3;           // sub-block 0..15 within segment
  const int tid  = (int)threadIdx.x;
  const int lane = tid & 63;
  const int wid  = tid >> 6;
  const int j0   = sub * PPB;
  const int td   = b & 1;
  const float* xg = x + (size_t)b * NPTS * CDIM;
  unsigned long long* seg = slots + (size_t)b * KSEL * BPS;
  unsigned long long* prb = probe + (size_t)b * KSEL * BPS;

  // ---- zero own probe slots through the L2 path (plain stores) ----
  if (tid >= 1 && tid < KSEL)
    store_plain(&prb[tid * BPS + sub], 0ull);

  // ---- one-time load: coords -> VGPRs (laundered), sq sequential ----
  float xr0[CDIM], xr1[CDIM];
  float sqr0, sqr1, df0, df1;
  {
    const float* src0 = xg + (size_t)(j0 + tid) * CDIM;
    float acc = 0.0f;
    {
#pragma clang fp contract(off)
#pragma unroll
      for (int c = 0; c < CDIM; ++c) { float v = src0[c]; xr0[c] = v; acc = acc + v * v; }
    }
    sqr0 = acc; df0 = 50000.0f;
    sqr1 = 0.0f; df1 = 50000.0f;
#pragma unroll
    for (int c = 0; c < CDIM; ++c) xr1[c] = 0.0f;
    if (tid < TAILN) {
      const float* src1 = xg + (size_t)(j0 + BLK + tid) * CDIM;
      float acc1 = 0.0f;
      {
#pragma clang fp contract(off)
#pragma unroll
        for (int c = 0; c < CDIM; ++c) { float v = src1[c]; xr1[c] = v; acc1 = acc1 + v * v; }
      }
      sqr1 = acc1;
    }
#pragma unroll
    for (int c = 0; c < CDIM; ++c) {
      asm volatile("" : "+v"(xr0[c]));
      asm volatile("" : "+v"(xr1[c]));
    }
    asm volatile("" : "+v"(sqr0));
    asm volatile("" : "+v"(sqr1));
  }

  // ---- per-segment ready-barrier on LLC slot row 0 (R4-proven path) ----
  asm volatile("s_waitcnt vmcnt(0)" ::: "memory");   // probe zeros issued
  if (tid == 0)
    __hip_atomic_store(&seg[sub], 1ull, __ATOMIC_RELAXED, __HIP_MEMORY_SCOPE_AGENT);
  if (tid < BPS) {
    while (__hip_atomic_load(&seg[tid], __ATOMIC_RELAXED,
                             __HIP_MEMORY_SCOPE_AGENT) == 0ull) {}
  }
  __syncthreads();

  int far;
  { int f = init_[b] % NPTS; if (f < 0) f += NPTS; far = f; }  // jnp.remainder
  if (sub == 0 && wid == 0) {          // fused output, row 0
    if (lane == 0) sidx[b * KSEL] = (float)(far + td * NPTS);
    if (lane < 32) patches[(size_t)(b * KSEL) * 32 + lane] = xg[(size_t)far * CDIM + lane];
  }

  int cap = 8, fails = 0;              // adaptive scalar-poll latch (per wave)

  // ---- 127 sequential FPS steps ----
  for (int step = 1; step < KSEL; ++step) {
    const int fu = __builtin_amdgcn_readfirstlane(far);
    const float* fx = xg + (size_t)fu * CDIM;
    float xf[CDIM];
#pragma unroll
    for (int c = 0; c < CDIM; ++c) xf[c] = fx[c];

    float sqf;
    {
#pragma clang fp contract(off)
      float a = 0.0f;
#pragma unroll
      for (int c = 0; c < CDIM; ++c) { float t = xf[c]; a = a + t * t; }
      sqf = a;
    }

    unsigned long long bk;
    {
      float dot = 0.0f;
#pragma unroll
      for (int c = 0; c < CDIM; ++c)
        dot = __builtin_fmaf(xf[c], xr0[c], dot);          // k-sequential FMA
      float d2;
      {
#pragma clang fp contract(off)
        d2 = (sqf + sqr0) - 2.0f * dot;                    // reference order
      }
      d2 = fmaxf(d2, 0.0f);
      float d = __fsqrt_rn(d2);
      const int j = j0 + tid;
      d = (j == far) ? -1.0f : d;                          // diagonal = -1
      float nd = fminf(d, df0);                            // f32 min-carry
      df0 = nd;
      bk = key_of(nd, j);
    }
    if (tid < TAILN) {
      float dot = 0.0f;
#pragma unroll
      for (int c = 0; c < CDIM; ++c)
        dot = __builtin_fmaf(xf[c], xr1[c], dot);
      float d2;
      {
#pragma clang fp contract(off)
        d2 = (sqf + sqr1) - 2.0f * dot;
      }
      d2 = fmaxf(d2, 0.0f);
      float d = __fsqrt_rn(d2);
      const int j = j0 + BLK + tid;
      d = (j == far) ? -1.0f : d;
      float nd = fminf(d, df1);
      df1 = nd;
      bk = kmax(bk, key_of(nd, j));
    }

    bk = wave_kmax64(bk);
    if (lane == 0) wk[wid] = bk;
    __syncthreads();                                       // barrier 1 (only barrier)

    if (tid == 0) {
      unsigned long long m = kmax(kmax(wk[0], wk[1]), kmax(wk[2], wk[3]));
      store_plain(&prb[step * BPS + sub], m);              // XCD-L2 probe
      __hip_atomic_store(&seg[step * BPS + sub], m,        // LLC (guaranteed)
                         __ATOMIC_RELAXED, __HIP_MEMORY_SCOPE_AGENT);
    }
    asm volatile("" ::: "memory");

    // ---- per-wave winner discovery ----
    bool got = false;
    if (cap > 0) {
      const unsigned long long* srow = prb + (size_t)step * BPS;
      for (int it = 0; it < cap && !got; ++it) {
        unsigned long long k0,k1,k2,k3,k4,k5,k6,k7,k8,k9,k10,k11,k12,k13,k14,k15;
        asm volatile(
            "s_dcache_inv\n\t"
            "s_load_dwordx2 %[a0],  %[bp], 0x0\n\t"
            "s_load_dwordx2 %[a1],  %[bp], 0x8\n\t"
            "s_load_dwordx2 %[a2],  %[bp], 0x10\n\t"
            "s_load_dwordx2 %[a3],  %[bp], 0x18\n\t"
            "s_load_dwordx2 %[a4],  %[bp], 0x20\n\t"
            "s_load_dwordx2 %[a5],  %[bp], 0x28\n\t"
            "s_load_dwordx2 %[a6],  %[bp], 0x30\n\t"
            "s_load_dwordx2 %[a7],  %[bp], 0x38\n\t"
            "s_load_dwordx2 %[a8],  %[bp], 0x40\n\t"
            "s_load_dwordx2 %[a9],  %[bp], 0x48\n\t"
            "s_load_dwordx2 %[a10], %[bp], 0x50\n\t"
            "s_load_dwordx2 %[a11], %[bp], 0x58\n\t"
            "s_load_dwordx2 %[a12], %[bp], 0x60\n\t"
            "s_load_dwordx2 %[a13], %[bp], 0x68\n\t"
            "s_load_dwordx2 %[a14], %[bp], 0x70\n\t"
            "s_load_dwordx2 %[a15], %[bp], 0x78\n\t"
            "s_waitcnt lgkmcnt(0)"
            : [a0]"=s"(k0),  [a1]"=s"(k1),  [a2]"=s"(k2),  [a3]"=s"(k3),
              [a4]"=s"(k4),  [a5]"=s"(k5),  [a6]"=s"(k6),  [a7]"=s"(k7),
              [a8]"=s"(k8),  [a9]"=s"(k9),  [a10]"=s"(k10),[a11]"=s"(k11),
              [a12]"=s"(k12),[a13]"=s"(k13),[a14]"=s"(k14),[a15]"=s"(k15)
            : [bp]"s"(srow)
            : "memory");
        // all-published check: every lo word (NPTS-j >= 1) nonzero
        unsigned int mn = (unsigned int)k0;
        mn = mn < (unsigned int)k1  ? mn : (unsigned int)k1;
        mn = mn < (unsigned int)k2  ? mn : (unsigned int)k2;
        mn = mn < (unsigned int)k3  ? mn : (unsigned int)k3;
        mn = mn < (unsigned int)k4  ? mn : (unsigned int)k4;
        mn = mn < (unsigned int)k5  ? mn : (unsigned int)k5;
        mn = mn < (unsigned int)k6  ? mn : (unsigned int)k6;
        mn = mn < (unsigned int)k7  ? mn : (unsigned int)k7;
        mn = mn < (unsigned int)k8  ? mn : (unsigned int)k8;
        mn = mn < (unsigned int)k9  ? mn : (unsigned int)k9;
        mn = mn < (unsigned int)k10 ? mn : (unsigned int)k10;
        mn = mn < (unsigned int)k11 ? mn : (unsigned int)k11;
        mn = mn < (unsigned int)k12 ? mn : (unsigned int)k12;
        mn = mn < (unsigned int)k13 ? mn : (unsigned int)k13;
        mn = mn < (unsigned int)k14 ? mn : (unsigned int)k14;
        mn = mn < (unsigned int)k15 ? mn : (unsigned int)k15;
        if (mn != 0u) {
          unsigned long long mx = kmax(kmax(kmax(k0, k1), kmax(k2, k3)),
                                       kmax(kmax(k4, k5), kmax(k6, k7)));
          mx = kmax(mx, kmax(kmax(kmax(k8, k9), kmax(k10, k11)),
                             kmax(kmax(k12, k13), kmax(k14, k15))));
          far = NPTS - (int)(unsigned int)(mx & 0xFFFFFFFFull);
          got = true;
        }
      }
      if (!got && ++fails >= 2) cap = 0;   // co-location false: stop trying
    }
    if (!got) {
      // proven vector LLC poll (guaranteed progress via agent store)
      unsigned long long k = (lane < BPS) ? 0ull : ~0ull;
      const unsigned long long* sp = &seg[(size_t)step * BPS + (lane & 15)];
      while (__any(k == 0ull)) {
        if (k == 0ull) k = merge64(k, load_llc(sp));
      }
      k = row16_kmax(k);                   // row-0 reduce; readlane(15) -> all
      far = NPTS - (int)(unsigned int)(k & 0xFFFFFFFFull);
    }

    if (sub == 0 && wid == 0) {            // fused output row `step`
      if (lane == 0) sidx[b * KSEL + step] = (float)(far + td * NPTS);
      if (lane < 32) patches[(size_t)(b * KSEL + step) * 32 + lane] =
                         xg[(size_t)far * CDIM + lane];
    }
  }
}

extern "C" void kernel_launch(void* const* d_in, const int* in_sizes, int n_in,
                              void* d_out, int out_size, void* d_ws, size_t ws_size,
                              hipStream_t stream) {
  const float* x    = (const float*)d_in[0];
  const int*   init = (const int*)d_in[1];
  (void)in_sizes; (void)n_in; (void)out_size; (void)ws_size;

  const size_t arr = (size_t)BT * KSEL * BPS * sizeof(unsigned long long);
  unsigned long long* slots = (unsigned long long*)d_ws;
  unsigned long long* probe = (unsigned long long*)((char*)d_ws + arr);

  float* patches = (float*)d_out;
  float* sidx    = patches + (size_t)4 * 256 * 32;

  hipMemsetAsync(d_ws, 0, 2 * arr, stream);

  void* kargs[] = { (void*)&x, (void*)&init, (void*)&patches, (void*)&sidx,
                    (void*)&slots, (void*)&probe };
  hipLaunchCooperativeKernel((const void*)fps_kernel, dim3(NB), dim3(BLK),
                             kargs, 0, stream);
}